// Round 4
// baseline (975.307 us; speedup 1.0000x reference)
//
#include <hip/hip_runtime.h>
#include <hip/hip_fp16.h>

#define NN 100000
#define EE 1200000
#define DD 64
#define CC 40
#define KK 16
#define SCAN_BLOCKS ((NN + 255) / 256)  // 391
#define NPB 128                         // nodes per spmm block
#define NBLK ((NN + NPB - 1) / NPB)     // 782
#define ECAP 4096                       // LDS edge-record capacity per block

// ---------- degree histogram ----------
__global__ __launch_bounds__(256) void deg_kernel(const int* __restrict__ dst,
                                                  int* __restrict__ cnt) {
    int e = blockIdx.x * 256 + threadIdx.x;
    if (e < EE) atomicAdd(&cnt[dst[e]], 1);
}

// ---------- dinv[i] = rsqrt(indeg+1) ----------
__global__ __launch_bounds__(256) void dinv_kernel(const int* __restrict__ cnt,
                                                   float* __restrict__ dinv) {
    int i = blockIdx.x * 256 + threadIdx.x;
    if (i < NN) dinv[i] = rsqrtf((float)(cnt[i] + 1));
}

// ---------- 3-phase coalesced exclusive scan ----------
__global__ __launch_bounds__(256) void scan1_kernel(const int* __restrict__ cnt,
                                                    int* __restrict__ row_ptr,
                                                    int* __restrict__ bsum) {
    __shared__ int sm[256];
    int t = threadIdx.x;
    int i = blockIdx.x * 256 + t;
    int v = (i < NN) ? cnt[i] : 0;
    sm[t] = v;
    __syncthreads();
    for (int off = 1; off < 256; off <<= 1) {
        int u = (t >= off) ? sm[t - off] : 0;
        __syncthreads();
        sm[t] += u;
        __syncthreads();
    }
    if (i < NN) row_ptr[i] = sm[t] - v;
    if (t == 255) bsum[blockIdx.x] = sm[255];
}

__global__ __launch_bounds__(512) void scan2_kernel(const int* __restrict__ bsum,
                                                    int* __restrict__ boff) {
    __shared__ int sm[512];
    int t = threadIdx.x;
    int v = (t < SCAN_BLOCKS) ? bsum[t] : 0;
    sm[t] = v;
    __syncthreads();
    for (int off = 1; off < 512; off <<= 1) {
        int u = (t >= off) ? sm[t - off] : 0;
        __syncthreads();
        sm[t] += u;
        __syncthreads();
    }
    if (t < SCAN_BLOCKS) boff[t] = sm[t] - v;
}

__global__ __launch_bounds__(256) void scan3_kernel(int* __restrict__ row_ptr,
                                                    const int* __restrict__ boff) {
    int i = blockIdx.x * 256 + threadIdx.x;
    if (i < NN) row_ptr[i] += boff[blockIdx.x];
    if (i == 0) row_ptr[NN] = EE;
}

// ---------- dst-range-sharded CSR scatter ----------
// blockIdx%8 selects a dst range (12500 nodes -> 1.2MB er region). With the
// typical round-robin block->XCD mapping, each er region is written by one
// XCD only -> lines stay L2-resident until full -> no E*64B write amp.
// Correctness does NOT depend on the mapping: every (range, edge-chunk) pair
// is processed exactly once.
__global__ __launch_bounds__(256) void scatter_kernel(
    const int* __restrict__ src, const int* __restrict__ dst,
    const int* __restrict__ row_ptr, int* __restrict__ cursor,
    int2* __restrict__ er, const float* __restrict__ dinv) {
    int r = blockIdx.x & 7;
    int cid = blockIdx.x >> 3;
    int lo = r * (NN / 8), hi = lo + (NN / 8);
    int e0 = cid * 2048 + threadIdx.x;
#pragma unroll
    for (int it = 0; it < 8; ++it) {
        int e = e0 + it * 256;
        if (e < EE) {
            int d = dst[e];
            if (d >= lo && d < hi) {
                int s = src[e];
                int pos = row_ptr[d] + atomicAdd(&cursor[d], 1);
                er[pos] = make_int2(s, __float_as_int(dinv[d] * dinv[s]));
            }
        }
    }
}

// ---------- feat (fp32, [N][64]) -> x0 (fp16, chunked [4][N][16]) ----------
__global__ __launch_bounds__(256) void cvt_kernel(const float4* __restrict__ feat4,
                                                  float4* __restrict__ xh) {
    int idx = blockIdx.x * 256 + threadIdx.x;  // (node, li)
    if (idx >= NN * 2) return;
    int node = idx >> 1, li = idx & 1;
    const float4* f = feat4 + node * 16 + li * 2;
#pragma unroll
    for (int c = 0; c < 4; ++c) {
        float4 u = f[c * 4], v = f[c * 4 + 1];
        float4 ov;
        __half2* op = (__half2*)&ov;
        op[0] = __floats2half2_rn(u.x, u.y);
        op[1] = __floats2half2_rn(u.z, u.w);
        op[2] = __floats2half2_rn(v.x, v.y);
        op[3] = __floats2half2_rn(v.z, v.w);
        xh[(size_t)c * (NN * 2) + node * 2 + li] = ov;
    }
}

// ---------- fused SpMM (pull, fp16 x, dim-chunked for L2 residency) ----------
// grid (NBLK, 4): blockIdx.y = dim chunk (16 dims = 32B/node -> 3.2MB, fits
// per-XCD L2). 2 lanes/node. er slice for the block's 128 nodes staged in LDS.
// mode: 0 = no h update, 1 = h update, 2 = h update + analytic feat term
__global__ __launch_bounds__(256) void spmm_step(
    const float4* __restrict__ x, float4* __restrict__ x_out,
    float4* __restrict__ h4, const float4* __restrict__ feat4,
    const int* __restrict__ row_ptr, const int2* __restrict__ er,
    const float* __restrict__ dinv, int mode) {
    __shared__ int2 se[ECAP];
    int t = threadIdx.x;
    int chunk = blockIdx.y;
    int n0 = blockIdx.x * NPB;
    int nend = n0 + NPB; if (nend > NN) nend = NN;
    int beg_blk = row_ptr[n0];
    int end_blk = row_ptr[nend];
    int cnt = end_blk - beg_blk;
    if (cnt <= ECAP) {
        for (int i = t; i < cnt; i += 256) se[i] = er[beg_blk + i];
    }
    __syncthreads();
    int node = n0 + (t >> 1);
    int li = t & 1;
    if (node >= NN) return;
    int beg = row_ptr[node] - beg_blk;
    int end = row_ptr[node + 1] - beg_blk;
    float di = dinv[node];
    float w0 = di * di;
    const float4* xc = x + (size_t)chunk * (NN * 2);
    int base = node * 2 + li;
    float4 sv = xc[base];
    float a0, a1, a2, a3, a4, a5, a6, a7;
    {
        const __half2* hp = (const __half2*)&sv;
        float2 f0 = __half22float2(hp[0]), f1 = __half22float2(hp[1]);
        float2 f2 = __half22float2(hp[2]), f3 = __half22float2(hp[3]);
        a0 = w0 * f0.x; a1 = w0 * f0.y; a2 = w0 * f1.x; a3 = w0 * f1.y;
        a4 = w0 * f2.x; a5 = w0 * f2.y; a6 = w0 * f3.x; a7 = w0 * f3.y;
    }
#define ACC8(WW, V)                                                         \
    {                                                                       \
        const __half2* hp = (const __half2*)&(V);                           \
        float2 f0 = __half22float2(hp[0]), f1 = __half22float2(hp[1]);      \
        float2 f2 = __half22float2(hp[2]), f3 = __half22float2(hp[3]);      \
        a0 = fmaf((WW), f0.x, a0); a1 = fmaf((WW), f0.y, a1);               \
        a2 = fmaf((WW), f1.x, a2); a3 = fmaf((WW), f1.y, a3);               \
        a4 = fmaf((WW), f2.x, a4); a5 = fmaf((WW), f2.y, a5);               \
        a6 = fmaf((WW), f3.x, a6); a7 = fmaf((WW), f3.y, a7);               \
    }
    if (cnt <= ECAP) {
        int e = beg, e4 = beg + ((end - beg) & ~3);
        for (; e < e4; e += 4) {
            int2 r0 = se[e], r1 = se[e + 1], r2 = se[e + 2], r3 = se[e + 3];
            float4 v0 = xc[r0.x * 2 + li];
            float4 v1 = xc[r1.x * 2 + li];
            float4 v2 = xc[r2.x * 2 + li];
            float4 v3 = xc[r3.x * 2 + li];
            ACC8(__int_as_float(r0.y), v0); ACC8(__int_as_float(r1.y), v1);
            ACC8(__int_as_float(r2.y), v2); ACC8(__int_as_float(r3.y), v3);
        }
        for (; e < end; ++e) {
            int2 r = se[e];
            float4 v = xc[r.x * 2 + li];
            ACC8(__int_as_float(r.y), v);
        }
    } else {  // fallback: slice too big for LDS (never hit for Poisson(12))
        int e = beg, e4 = beg + ((end - beg) & ~3);
        for (; e < e4; e += 4) {
            int2 r0 = er[beg_blk + e], r1 = er[beg_blk + e + 1];
            int2 r2 = er[beg_blk + e + 2], r3 = er[beg_blk + e + 3];
            float4 v0 = xc[r0.x * 2 + li];
            float4 v1 = xc[r1.x * 2 + li];
            float4 v2 = xc[r2.x * 2 + li];
            float4 v3 = xc[r3.x * 2 + li];
            ACC8(__int_as_float(r0.y), v0); ACC8(__int_as_float(r1.y), v1);
            ACC8(__int_as_float(r2.y), v2); ACC8(__int_as_float(r3.y), v3);
        }
        for (; e < end; ++e) {
            int2 r = er[beg_blk + e];
            float4 v = xc[r.x * 2 + li];
            ACC8(__int_as_float(r.y), v);
        }
    }
#undef ACC8
    float4 ov;
    __half2* op = (__half2*)&ov;
    op[0] = __floats2half2_rn(a0, a1);
    op[1] = __floats2half2_rn(a2, a3);
    op[2] = __floats2half2_rn(a4, a5);
    op[3] = __floats2half2_rn(a6, a7);
    x_out[(size_t)chunk * (NN * 2) + base] = ov;
    if (mode) {
        size_t hb = (size_t)chunk * (NN * 4) + node * 4 + li * 2;
        float4 h0 = h4[hb], h1 = h4[hb + 1];
        h0.x = (h0.x + 0.95f * a0) * (1.0f / 16.0f);
        h0.y = (h0.y + 0.95f * a1) * (1.0f / 16.0f);
        h0.z = (h0.z + 0.95f * a2) * (1.0f / 16.0f);
        h0.w = (h0.w + 0.95f * a3) * (1.0f / 16.0f);
        h1.x = (h1.x + 0.95f * a4) * (1.0f / 16.0f);
        h1.y = (h1.y + 0.95f * a5) * (1.0f / 16.0f);
        h1.z = (h1.z + 0.95f * a6) * (1.0f / 16.0f);
        h1.w = (h1.w + 0.95f * a7) * (1.0f / 16.0f);
        if (mode == 2) {
            const float FC = 0.05f / 15.0f;  // analytic sum of all 16 feat terms
            size_t fb = (size_t)node * 16 + chunk * 4 + li * 2;
            float4 f0 = feat4[fb], f1 = feat4[fb + 1];
            h0.x = fmaf(FC, f0.x, h0.x); h0.y = fmaf(FC, f0.y, h0.y);
            h0.z = fmaf(FC, f0.z, h0.z); h0.w = fmaf(FC, f0.w, h0.w);
            h1.x = fmaf(FC, f1.x, h1.x); h1.y = fmaf(FC, f1.y, h1.y);
            h1.z = fmaf(FC, f1.z, h1.z); h1.w = fmaf(FC, f1.w, h1.w);
        }
        h4[hb] = h0; h4[hb + 1] = h1;
    }
}

// ---------- FC epilogue (h is chunked [4][N][16] fp32) ----------
__global__ __launch_bounds__(256) void fc_kernel(const float4* __restrict__ h4,
                                                 const float* __restrict__ W,
                                                 const float* __restrict__ b,
                                                 float* __restrict__ out) {
    __shared__ float Ws[CC * 68];
    __shared__ float bs[CC];
    for (int j = threadIdx.x; j < CC * DD; j += 256) {
        int c = j >> 6, d = j & 63;
        Ws[c * 68 + d] = W[j];
    }
    if (threadIdx.x < CC) bs[threadIdx.x] = b[threadIdx.x];
    __syncthreads();
    int idx = blockIdx.x * 256 + threadIdx.x;
    if (idx >= NN * CC) return;
    int i = idx / CC, c = idx - i * CC;
    const float* wr = Ws + c * 68;
    float acc = bs[c];
#pragma unroll
    for (int ch = 0; ch < 4; ++ch) {
#pragma unroll
        for (int q = 0; q < 4; ++q) {
            float4 a = h4[(size_t)ch * (NN * 4) + i * 4 + q];
            int d = ch * 16 + q * 4;
            acc = fmaf(a.x, wr[d + 0], acc);
            acc = fmaf(a.y, wr[d + 1], acc);
            acc = fmaf(a.z, wr[d + 2], acc);
            acc = fmaf(a.w, wr[d + 3], acc);
        }
    }
    out[idx] = acc;
}

extern "C" void kernel_launch(void* const* d_in, const int* in_sizes, int n_in,
                              void* d_out, int out_size, void* d_ws, size_t ws_size,
                              hipStream_t stream) {
    const float* feat = (const float*)d_in[0];
    const float* W    = (const float*)d_in[1];
    const float* b    = (const float*)d_in[2];
    const int*   src  = (const int*)d_in[3];
    const int*   dst  = (const int*)d_in[4];
    float* out = (float*)d_out;

    char* p = (char*)d_ws;
    auto alloc = [&](size_t bytes) {
        char* r = p;
        p += (bytes + 255) & ~(size_t)255;
        return r;
    };
    int*      cnt     = (int*)alloc((size_t)NN * sizeof(int));
    int*      cursor  = (int*)alloc((size_t)NN * sizeof(int));
    float*    dinv    = (float*)alloc((size_t)NN * sizeof(float));
    int*      row_ptr = (int*)alloc((size_t)(NN + 1) * sizeof(int));
    int*      bsum    = (int*)alloc((size_t)SCAN_BLOCKS * sizeof(int));
    int*      boff    = (int*)alloc((size_t)SCAN_BLOCKS * sizeof(int));
    int2*     er      = (int2*)alloc((size_t)EE * sizeof(int2));
    float4*   xh0     = (float4*)alloc((size_t)NN * 8 * sizeof(float4));
    float4*   xh1     = (float4*)alloc((size_t)NN * 8 * sizeof(float4));
    float4*   h       = (float4*)alloc((size_t)NN * 16 * sizeof(float4));

    hipMemsetAsync(cnt, 0, (size_t)NN * sizeof(int), stream);
    hipMemsetAsync(cursor, 0, (size_t)NN * sizeof(int), stream);
    hipMemsetAsync(h, 0, (size_t)NN * 16 * sizeof(float4), stream);

    deg_kernel<<<(EE + 255) / 256, 256, 0, stream>>>(dst, cnt);
    dinv_kernel<<<(NN + 255) / 256, 256, 0, stream>>>(cnt, dinv);
    scan1_kernel<<<SCAN_BLOCKS, 256, 0, stream>>>(cnt, row_ptr, bsum);
    scan2_kernel<<<1, 512, 0, stream>>>(bsum, boff);
    scan3_kernel<<<SCAN_BLOCKS, 256, 0, stream>>>(row_ptr, boff);
    // 586 edge-chunks x 8 dst-ranges
    scatter_kernel<<<((EE + 2047) / 2048) * 8, 256, 0, stream>>>(src, dst, row_ptr,
                                                                 cursor, er, dinv);
    cvt_kernel<<<(NN * 2 + 255) / 256, 256, 0, stream>>>((const float4*)feat, xh0);

    const float4* xs = xh0;
    float4* xd = xh1;
    for (int j = 0; j < KK; ++j) {
        int mode = (j >= 10) ? ((j == KK - 1) ? 2 : 1) : 0;
        spmm_step<<<dim3(NBLK, 4), 256, 0, stream>>>(xs, xd, h, (const float4*)feat,
                                                     row_ptr, er, dinv, mode);
        const float4* t = xd;
        xd = (xd == xh0) ? xh1 : xh0;
        xs = (float4*)t;
    }
    fc_kernel<<<(NN * CC + 255) / 256, 256, 0, stream>>>(h, W, b, out);
}

// Round 5
// 678.009 us; speedup vs baseline: 1.4385x; 1.4385x over previous
//
#include <hip/hip_runtime.h>
#include <hip/hip_fp16.h>

#define NN 100000
#define EE 1200000
#define DD 64
#define CC 40
#define KK 16
#define SCAN_BLOCKS ((NN + 255) / 256)  // 391
#define BSZ 196                          // nodes per sort bucket
#define NBK 512                          // buckets (512*196 = 100352 >= NN)
#define EPB 4096                         // edges per phase-A block
#define ABLK ((EE + EPB - 1) / EPB)      // 293
#define BCAP 3072                        // phase-B LDS capacity (mean 2344, 15 sigma)

struct __align__(8) ERec { int c; float w; };

// ---------- degree histogram ----------
__global__ __launch_bounds__(256) void deg_kernel(const int* __restrict__ dst,
                                                  int* __restrict__ cnt) {
    int e = blockIdx.x * 256 + threadIdx.x;
    if (e < EE) atomicAdd(&cnt[dst[e]], 1);
}

// ---------- dinv[i] = rsqrt(indeg+1) ----------
__global__ __launch_bounds__(256) void dinv_kernel(const int* __restrict__ cnt,
                                                   float* __restrict__ dinv) {
    int i = blockIdx.x * 256 + threadIdx.x;
    if (i < NN) dinv[i] = rsqrtf((float)(cnt[i] + 1));
}

// ---------- 3-phase coalesced exclusive scan ----------
__global__ __launch_bounds__(256) void scan1_kernel(const int* __restrict__ cnt,
                                                    int* __restrict__ row_ptr,
                                                    int* __restrict__ bsum) {
    __shared__ int sm[256];
    int t = threadIdx.x;
    int i = blockIdx.x * 256 + t;
    int v = (i < NN) ? cnt[i] : 0;
    sm[t] = v;
    __syncthreads();
    for (int off = 1; off < 256; off <<= 1) {
        int u = (t >= off) ? sm[t - off] : 0;
        __syncthreads();
        sm[t] += u;
        __syncthreads();
    }
    if (i < NN) row_ptr[i] = sm[t] - v;
    if (t == 255) bsum[blockIdx.x] = sm[255];
}

__global__ __launch_bounds__(512) void scan2_kernel(const int* __restrict__ bsum,
                                                    int* __restrict__ boff) {
    __shared__ int sm[512];
    int t = threadIdx.x;
    int v = (t < SCAN_BLOCKS) ? bsum[t] : 0;
    sm[t] = v;
    __syncthreads();
    for (int off = 1; off < 512; off <<= 1) {
        int u = (t >= off) ? sm[t - off] : 0;
        __syncthreads();
        sm[t] += u;
        __syncthreads();
    }
    if (t < SCAN_BLOCKS) boff[t] = sm[t] - v;
}

__global__ __launch_bounds__(256) void scan3_kernel(int* __restrict__ row_ptr,
                                                    const int* __restrict__ boff) {
    int i = blockIdx.x * 256 + threadIdx.x;
    if (i < NN) row_ptr[i] += boff[blockIdx.x];
    if (i == 0) row_ptr[NN] = EE;
}

// ---------- bucket cursor init: cursor[s] = row_ptr[first node of bucket] ----------
__global__ __launch_bounds__(512) void curinit_kernel(const int* __restrict__ row_ptr,
                                                      int* __restrict__ cursor) {
    int s = threadIdx.x;
    if (s < NBK) {
        int n = s * BSZ; if (n > NN) n = NN;
        cursor[s] = row_ptr[n];
    }
}

// ---------- sort phase A: LDS-bin 4096 edges into 512 buckets, write runs ----------
// Output tmp[(dst,src)] grouped by bucket; per-bucket runs are coalesced (~64B),
// each line written whole from one CU -> no E*64B write amplification.
__global__ __launch_bounds__(256) void sortA_kernel(const int* __restrict__ src,
                                                    const int* __restrict__ dst,
                                                    int* __restrict__ cursor,
                                                    int2* __restrict__ tmp) {
    __shared__ int2 stg[EPB];                 // 32KB
    __shared__ int hist[NBK], loff[NBK], lcur[NBK], gbase[NBK];  // 8KB
    int t = threadIdx.x;
    long e0 = (long)blockIdx.x * EPB;
    int n = (int)((EE - e0 < EPB) ? (EE - e0) : EPB);
    for (int j = t; j < NBK; j += 256) hist[j] = 0;
    __syncthreads();
    int d[16], sx[16];
#pragma unroll
    for (int j = 0; j < 16; ++j) {
        int i = t + j * 256;
        if (i < n) {
            d[j] = dst[e0 + i];
            sx[j] = src[e0 + i];
            atomicAdd(&hist[d[j] / BSZ], 1);
        } else d[j] = -1;
    }
    __syncthreads();
    // exclusive scan of hist[512] with 256 threads (2 elems each)
    int c0 = hist[2 * t], c1 = hist[2 * t + 1];
    int s2 = c0 + c1;
    __syncthreads();
    loff[t] = s2;  // temp: per-thread sums in loff[0..255]
    __syncthreads();
    for (int off = 1; off < 256; off <<= 1) {
        int u = (t >= off) ? loff[t - off] : 0;
        __syncthreads();
        loff[t] += u;
        __syncthreads();
    }
    int excl = loff[t] - s2;
    __syncthreads();  // done with temp usage
    loff[2 * t] = excl;          loff[2 * t + 1] = excl + c0;
    lcur[2 * t] = excl;          lcur[2 * t + 1] = excl + c0;
    gbase[2 * t]     = atomicAdd(&cursor[2 * t], c0);
    gbase[2 * t + 1] = atomicAdd(&cursor[2 * t + 1], c1);
    __syncthreads();
#pragma unroll
    for (int j = 0; j < 16; ++j) {
        if (d[j] >= 0) {
            int b = d[j] / BSZ;
            int p = atomicAdd(&lcur[b], 1);
            stg[p] = make_int2(d[j], sx[j]);
        }
    }
    __syncthreads();
    for (int i = t; i < n; i += 256) {
        int2 r = stg[i];
        int b = r.x / BSZ;
        tmp[gbase[b] + (i - loff[b])] = r;  // consecutive within runs -> coalesced
    }
}

// ---------- sort phase B: exact counting sort within bucket, coalesced er write ----------
__global__ __launch_bounds__(256) void sortB_kernel(const int2* __restrict__ tmp,
                                                    const int* __restrict__ row_ptr,
                                                    const float* __restrict__ dinv,
                                                    int2* __restrict__ er) {
    __shared__ int2 se[BCAP];     // 24KB
    __shared__ int2 so[BCAP];     // 24KB
    __shared__ int hist[256], lcur[256];
    __shared__ float sdinv[BSZ];
    int s = blockIdx.x;
    int n0 = s * BSZ;
    if (n0 >= NN) return;
    int n1 = n0 + BSZ; if (n1 > NN) n1 = NN;
    int nb = n1 - n0;
    int t = threadIdx.x;
    int seg0 = row_ptr[n0], seg1 = row_ptr[n1];
    int cnt = seg1 - seg0;
    hist[t] = 0;
    for (int i = t; i < nb; i += 256) sdinv[i] = dinv[n0 + i];
    __syncthreads();
    bool fit = (cnt <= BCAP);
    for (int i = t; i < cnt; i += 256) {
        int2 r = tmp[seg0 + i];
        if (fit) se[i] = r;
        atomicAdd(&hist[r.x - n0], 1);
    }
    __syncthreads();
    // exclusive scan of hist[256] -> running cursors
    int v = hist[t];
    lcur[t] = v;  // temp inclusive
    __syncthreads();
    for (int off = 1; off < 256; off <<= 1) {
        int u = (t >= off) ? lcur[t - off] : 0;
        __syncthreads();
        lcur[t] += u;
        __syncthreads();
    }
    int excl = lcur[t] - v;
    __syncthreads();
    lcur[t] = excl;
    __syncthreads();
    for (int i = t; i < cnt; i += 256) {
        int2 r = fit ? se[i] : tmp[seg0 + i];
        int ln = r.x - n0;
        int pos = atomicAdd(&lcur[ln], 1);
        float w = sdinv[ln] * dinv[r.y];
        int2 o = make_int2(r.y, __float_as_int(w));
        if (fit) so[pos] = o;
        else er[seg0 + pos] = o;  // overflow fallback (never hit statistically)
    }
    __syncthreads();
    if (fit)
        for (int i = t; i < cnt; i += 256) er[seg0 + i] = so[i];  // coalesced
}

// ---------- feat (fp32) -> x0 (fp16 rows [N][64]) ----------
__global__ __launch_bounds__(256) void cvt_kernel(const float2* __restrict__ feat2,
                                                  __half2* __restrict__ xh) {
    int i = blockIdx.x * 256 + threadIdx.x;
    if (i < NN * 32) {
        float2 f = feat2[i];
        xh[i] = __floats2half2_rn(f.x, f.y);
    }
}

// ---------- fused SpMM (pull, fp16 x) + SSGC h-update ----------
// 8 lanes/node (float4 = 8 halves each), 8 nodes/wave, unroll x4.
// mode: 0 = no h; 1 = h init (j==10); 2 = h accumulate; 3 = final (h acc +
// analytic feat term, skip x_out store)
__global__ __launch_bounds__(256) void spmm_step(
    const float4* __restrict__ x, float4* __restrict__ x_out,
    float4* __restrict__ h4, const float4* __restrict__ feat4,
    const int* __restrict__ row_ptr, const ERec* __restrict__ er,
    const float* __restrict__ dinv, int mode) {
    int g = (blockIdx.x * 256 + threadIdx.x) >> 3;  // node; grid exact NN*8 threads
    int li = threadIdx.x & 7;                       // owns dims [8li, 8li+8)
    int beg = row_ptr[g], end = row_ptr[g + 1];
    float di = dinv[g];
    float w0 = di * di;
    int base = g * 8 + li;
    float4 sv = x[base];
    float a0, a1, a2, a3, a4, a5, a6, a7;
    {
        const __half2* hp = (const __half2*)&sv;
        float2 f0 = __half22float2(hp[0]), f1 = __half22float2(hp[1]);
        float2 f2 = __half22float2(hp[2]), f3 = __half22float2(hp[3]);
        a0 = w0 * f0.x; a1 = w0 * f0.y; a2 = w0 * f1.x; a3 = w0 * f1.y;
        a4 = w0 * f2.x; a5 = w0 * f2.y; a6 = w0 * f3.x; a7 = w0 * f3.y;
    }
#define ACC8(R, V)                                                          \
    {                                                                       \
        const __half2* hp = (const __half2*)&(V);                           \
        float2 f0 = __half22float2(hp[0]), f1 = __half22float2(hp[1]);      \
        float2 f2 = __half22float2(hp[2]), f3 = __half22float2(hp[3]);      \
        a0 = fmaf((R).w, f0.x, a0); a1 = fmaf((R).w, f0.y, a1);             \
        a2 = fmaf((R).w, f1.x, a2); a3 = fmaf((R).w, f1.y, a3);             \
        a4 = fmaf((R).w, f2.x, a4); a5 = fmaf((R).w, f2.y, a5);             \
        a6 = fmaf((R).w, f3.x, a6); a7 = fmaf((R).w, f3.y, a7);             \
    }
    int e = beg;
    int e4 = beg + ((end - beg) & ~3);
    for (; e < e4; e += 4) {
        ERec r0 = er[e], r1 = er[e + 1], r2 = er[e + 2], r3 = er[e + 3];
        float4 v0 = x[r0.c * 8 + li];
        float4 v1 = x[r1.c * 8 + li];
        float4 v2 = x[r2.c * 8 + li];
        float4 v3 = x[r3.c * 8 + li];
        ACC8(r0, v0); ACC8(r1, v1); ACC8(r2, v2); ACC8(r3, v3);
    }
    for (; e < end; ++e) {
        ERec r = er[e];
        float4 v = x[r.c * 8 + li];
        ACC8(r, v);
    }
#undef ACC8
    if (mode != 3) {
        float4 ov;
        __half2* op = (__half2*)&ov;
        op[0] = __floats2half2_rn(a0, a1);
        op[1] = __floats2half2_rn(a2, a3);
        op[2] = __floats2half2_rn(a4, a5);
        op[3] = __floats2half2_rn(a6, a7);
        x_out[base] = ov;
    }
    if (mode) {
        int hb = g * 16 + li * 2;
        float4 h0, h1;
        if (mode == 1) {  // init: h was 0
            h0.x = 0.95f * a0 * (1.0f / 16.0f); h0.y = 0.95f * a1 * (1.0f / 16.0f);
            h0.z = 0.95f * a2 * (1.0f / 16.0f); h0.w = 0.95f * a3 * (1.0f / 16.0f);
            h1.x = 0.95f * a4 * (1.0f / 16.0f); h1.y = 0.95f * a5 * (1.0f / 16.0f);
            h1.z = 0.95f * a6 * (1.0f / 16.0f); h1.w = 0.95f * a7 * (1.0f / 16.0f);
        } else {
            h0 = h4[hb]; h1 = h4[hb + 1];
            h0.x = (h0.x + 0.95f * a0) * (1.0f / 16.0f);
            h0.y = (h0.y + 0.95f * a1) * (1.0f / 16.0f);
            h0.z = (h0.z + 0.95f * a2) * (1.0f / 16.0f);
            h0.w = (h0.w + 0.95f * a3) * (1.0f / 16.0f);
            h1.x = (h1.x + 0.95f * a4) * (1.0f / 16.0f);
            h1.y = (h1.y + 0.95f * a5) * (1.0f / 16.0f);
            h1.z = (h1.z + 0.95f * a6) * (1.0f / 16.0f);
            h1.w = (h1.w + 0.95f * a7) * (1.0f / 16.0f);
        }
        if (mode == 3) {
            const float FC = 0.05f / 15.0f;  // analytic sum of all 16 feat terms
            float4 f0 = feat4[hb], f1 = feat4[hb + 1];
            h0.x = fmaf(FC, f0.x, h0.x); h0.y = fmaf(FC, f0.y, h0.y);
            h0.z = fmaf(FC, f0.z, h0.z); h0.w = fmaf(FC, f0.w, h0.w);
            h1.x = fmaf(FC, f1.x, h1.x); h1.y = fmaf(FC, f1.y, h1.y);
            h1.z = fmaf(FC, f1.z, h1.z); h1.w = fmaf(FC, f1.w, h1.w);
        }
        h4[hb] = h0; h4[hb + 1] = h1;
    }
}

// ---------- FC epilogue ----------
__global__ __launch_bounds__(256) void fc_kernel(const float* __restrict__ h,
                                                 const float* __restrict__ W,
                                                 const float* __restrict__ b,
                                                 float* __restrict__ out) {
    __shared__ float Ws[CC * 68];
    __shared__ float bs[CC];
    for (int j = threadIdx.x; j < CC * DD; j += 256) {
        int c = j >> 6, d = j & 63;
        Ws[c * 68 + d] = W[j];
    }
    if (threadIdx.x < CC) bs[threadIdx.x] = b[threadIdx.x];
    __syncthreads();
    int idx = blockIdx.x * 256 + threadIdx.x;
    if (idx >= NN * CC) return;
    int i = idx / CC, c = idx - i * CC;
    const float4* h4 = (const float4*)(h + (long)i * DD);
    const float* wr = Ws + c * 68;
    float acc = bs[c];
#pragma unroll
    for (int d2 = 0; d2 < 16; ++d2) {
        float4 a = h4[d2];
        acc = fmaf(a.x, wr[d2 * 4 + 0], acc);
        acc = fmaf(a.y, wr[d2 * 4 + 1], acc);
        acc = fmaf(a.z, wr[d2 * 4 + 2], acc);
        acc = fmaf(a.w, wr[d2 * 4 + 3], acc);
    }
    out[idx] = acc;
}

extern "C" void kernel_launch(void* const* d_in, const int* in_sizes, int n_in,
                              void* d_out, int out_size, void* d_ws, size_t ws_size,
                              hipStream_t stream) {
    const float* feat = (const float*)d_in[0];
    const float* W    = (const float*)d_in[1];
    const float* b    = (const float*)d_in[2];
    const int*   src  = (const int*)d_in[3];
    const int*   dst  = (const int*)d_in[4];
    float* out = (float*)d_out;

    char* p = (char*)d_ws;
    auto alloc = [&](size_t bytes) {
        char* r = p;
        p += (bytes + 255) & ~(size_t)255;
        return r;
    };
    int*      cnt     = (int*)alloc((size_t)NN * sizeof(int));
    float*    dinv    = (float*)alloc((size_t)NN * sizeof(float));
    int*      row_ptr = (int*)alloc((size_t)(NN + 1) * sizeof(int));
    int*      bsum    = (int*)alloc((size_t)SCAN_BLOCKS * sizeof(int));
    int*      boff    = (int*)alloc((size_t)SCAN_BLOCKS * sizeof(int));
    int*      cursor  = (int*)alloc((size_t)NBK * sizeof(int));
    int2*     tmp     = (int2*)alloc((size_t)EE * sizeof(int2));
    int2*     er      = (int2*)alloc((size_t)EE * sizeof(int2));
    float4*   xh0     = (float4*)alloc((size_t)NN * 8 * sizeof(float4));
    float4*   xh1     = (float4*)alloc((size_t)NN * 8 * sizeof(float4));
    float*    h       = (float*)alloc((size_t)NN * DD * sizeof(float));

    hipMemsetAsync(cnt, 0, (size_t)NN * sizeof(int), stream);
    // no h memset needed: step j==10 initializes h (mode 1)

    deg_kernel<<<(EE + 255) / 256, 256, 0, stream>>>(dst, cnt);
    dinv_kernel<<<(NN + 255) / 256, 256, 0, stream>>>(cnt, dinv);
    scan1_kernel<<<SCAN_BLOCKS, 256, 0, stream>>>(cnt, row_ptr, bsum);
    scan2_kernel<<<1, 512, 0, stream>>>(bsum, boff);
    scan3_kernel<<<SCAN_BLOCKS, 256, 0, stream>>>(row_ptr, boff);
    curinit_kernel<<<1, 512, 0, stream>>>(row_ptr, cursor);
    sortA_kernel<<<ABLK, 256, 0, stream>>>(src, dst, cursor, tmp);
    sortB_kernel<<<NBK, 256, 0, stream>>>(tmp, row_ptr, dinv, er);
    cvt_kernel<<<(NN * 32 + 255) / 256, 256, 0, stream>>>((const float2*)feat,
                                                          (__half2*)xh0);

    const float4* xs = xh0;
    float4* xd = xh1;
    for (int j = 0; j < KK; ++j) {
        int mode = (j < 10) ? 0 : ((j == 10) ? 1 : ((j == KK - 1) ? 3 : 2));
        spmm_step<<<3125, 256, 0, stream>>>(xs, xd, (float4*)h, (const float4*)feat,
                                            row_ptr, (const ERec*)er, dinv, mode);
        const float4* t = xd;
        xd = (xd == xh0) ? xh1 : xh0;
        xs = t;
    }
    fc_kernel<<<(NN * CC + 255) / 256, 256, 0, stream>>>(h, W, b, out);
}